// Round 7
// baseline (156.867 us; speedup 1.0000x reference)
//
#include <hip/hip_runtime.h>
#include <hip/hip_bf16.h>

// 1-NN VQ via split-bf16 MFMA + exact fp32 refinement.
//   score[q][k] = csq[k] - 2*dot(q,c_k); out = argmin_k (lowest-k tie-break).
// Phase 0 (knn_prep): codebook -> bf16 hi/lo fragment-ready cbB + csq; zeroes cnt.
// Phase A (knn_mfma): 64 queries/block; q split to (qh,ql) bf16 in LDS;
//   dot ~= qh.ch + qh.cl + ql.ch (3-product; worst-case score err ~1.9e-3).
//   Top-2 per query via monotone u64 keys; gap < T=0.004 (>= 2x err bound)
//   -> worklist. Phase B (knn_refine): exact fp32 rescan, block-per-query.
// Round-7 changes vs r6: T 0.02->0.004 (r5/r6 evidence: refine was eating
//   ~90 us -> n was ~6k; now ~1.3k). Block 128q->64q: LDS 66.5->33 KB,
//   acc 128->64 VGPR, launch_bounds(256,4) -> 4 blk/CU (r6: 2 blk/CU,
//   Occ 20.7%, MfmaUtil 15.9% - B-load latency unhidden). memset folded
//   into prep. kb loops stay unroll 1 (r4: full unroll spills); epilogue
//   stays fully unrolled (r5: unroll-1 -> acc in scratch).

typedef __bf16 bf16x8 __attribute__((ext_vector_type(8)));
typedef float  floatx4 __attribute__((ext_vector_type(4)));
typedef unsigned uintx4 __attribute__((ext_vector_type(4)));

#define MFMA16 __builtin_amdgcn_mfma_f32_16x16x32_bf16

#define CNT_OFF 0
#define CSQ_OFF 1024
#define CBB_OFF 4096
#define WL_OFF  (4096 + 131072)
#define WL_CAP  32768
#define T_FLAG  0.004f

__device__ __forceinline__ unsigned fmap(float f) {
    unsigned u = __float_as_uint(f);
    return (u & 0x80000000u) ? ~u : (u | 0x80000000u);
}
__device__ __forceinline__ float unfmap(unsigned u) {
    unsigned b = (u & 0x80000000u) ? (u ^ 0x80000000u) : ~u;
    return __uint_as_float(b);
}

// ---------------- Phase 0: codebook split + fragment layout + csq + cnt=0 ----------------
__global__ void knn_prep(const float* __restrict__ cb, __bf16* __restrict__ cbB,
                         float* __restrict__ csq, int* __restrict__ cnt) {
    const int tid = threadIdx.x;
    const int id = blockIdx.x * 256 + tid;       // 0..8191
    if (id == 0) *cnt = 0;
    const int t = id >> 9;
    const int kb = (id >> 6) & 7;
    const int ln = id & 63;
    const int n = t * 16 + (ln & 15);
    const int part = kb >> 2;
    const int chunk = kb & 3;
    const int k0 = chunk * 32 + (ln >> 4) * 8;
    const float* src = cb + (size_t)n * 128 + k0;
    union { __bf16 h[8]; uintx4 u; } p;
#pragma unroll
    for (int j = 0; j < 8; ++j) {
        float f = src[j];
        __bf16 hh = (__bf16)f;
        p.h[j] = (part == 0) ? hh : (__bf16)(f - (float)hh);
    }
    *(uintx4*)(cbB + (size_t)id * 8) = p.u;

    if (blockIdx.x == 0) {
        const float4* row = (const float4*)(cb + (size_t)tid * 128);
        float a0 = 0.f, a1 = 0.f, a2 = 0.f, a3 = 0.f;
#pragma unroll 8
        for (int j = 0; j < 32; ++j) {
            float4 v = row[j];
            a0 = fmaf(v.x, v.x, a0);
            a1 = fmaf(v.y, v.y, a1);
            a2 = fmaf(v.z, v.z, a2);
            a3 = fmaf(v.w, v.w, a3);
        }
        csq[tid] = (a0 + a1) + (a2 + a3);
    }
}

// ---------------- Phase A: MFMA scores + top-2 + flag ----------------
__global__ __launch_bounds__(256, 4) void knn_mfma(const float* __restrict__ x,
                                                   const __bf16* __restrict__ cbB,
                                                   const float* __restrict__ csq_g,
                                                   int* __restrict__ out,
                                                   int* __restrict__ cnt,
                                                   int* __restrict__ wl) {
    __shared__ __bf16 sAf[4 * 8 * 64 * 8];   // [mt][kb][lane][8] = 32 KB
    __shared__ float s_csq[256];

    const int tid = threadIdx.x;
    const int wave = tid >> 6;
    const int lane = tid & 63;

    s_csq[tid] = csq_g[tid];

    // ---- convert 64-query tile to split bf16, fragment-ready in LDS ----
    const float* xblk = x + (size_t)blockIdx.x * 64 * 128;
    const int chunk = wave;                  // wave w converts channel chunk w
#pragma unroll 1
    for (int mt = 0; mt < 4; ++mt) {
        const int q = mt * 16 + (lane & 15);
        const int k0 = chunk * 32 + (lane >> 4) * 8;
        const float* src = xblk + (size_t)q * 128 + k0;
        float4 f0 = *(const float4*)(src);
        float4 f1 = *(const float4*)(src + 4);
        float f[8] = {f0.x, f0.y, f0.z, f0.w, f1.x, f1.y, f1.z, f1.w};
        union { __bf16 h[8]; uintx4 u; } ph, pl;
#pragma unroll
        for (int j = 0; j < 8; ++j) {
            __bf16 hh = (__bf16)f[j];
            ph.h[j] = hh;
            pl.h[j] = (__bf16)(f[j] - (float)hh);
        }
        *(uintx4*)(sAf + (((mt * 8 + chunk) * 64 + lane) * 8)) = ph.u;
        *(uintx4*)(sAf + (((mt * 8 + 4 + chunk) * 64 + lane) * 8)) = pl.u;
    }
    __syncthreads();

    // ---- main loop: wave owns m-tile `wave` x all 16 n-tiles ----
    floatx4 acc[16];
#pragma unroll
    for (int t = 0; t < 16; ++t) acc[t] = (floatx4){0.f, 0.f, 0.f, 0.f};

    const int mt = wave;

    // Part 1: B hi chunks (kb 0..3): qh.ch + ql.ch
#pragma unroll 1
    for (int kb = 0; kb < 4; ++kb) {
        bf16x8 ah = *(bf16x8*)(sAf + (((mt * 8 + kb) * 64 + lane) * 8));
        bf16x8 al = *(bf16x8*)(sAf + (((mt * 8 + 4 + kb) * 64 + lane) * 8));
        const __bf16* bbase = cbB + ((size_t)kb * 64 + lane) * 8;
#pragma unroll
        for (int t = 0; t < 16; ++t) {
            bf16x8 b = *(const bf16x8*)(bbase + (size_t)t * 4096);
            acc[t] = MFMA16(ah, b, acc[t], 0, 0, 0);
            acc[t] = MFMA16(al, b, acc[t], 0, 0, 0);
        }
    }
    // Part 2: B lo chunks (kb 4..7): qh.cl only (ql.cl dropped)
#pragma unroll 1
    for (int kb = 4; kb < 8; ++kb) {
        const int ca = kb & 3;
        bf16x8 ah = *(bf16x8*)(sAf + (((mt * 8 + ca) * 64 + lane) * 8));
        const __bf16* bbase = cbB + ((size_t)kb * 64 + lane) * 8;
#pragma unroll
        for (int t = 0; t < 16; ++t) {
            bf16x8 b = *(const bf16x8*)(bbase + (size_t)t * 4096);
            acc[t] = MFMA16(ah, b, acc[t], 0, 0, 0);
        }
    }

    // ---- epilogue: top-2 per query row, flag near-ties (FULLY unrolled) ----
    float cs[16];
#pragma unroll
    for (int t = 0; t < 16; ++t) cs[t] = s_csq[t * 16 + (lane & 15)];

#pragma unroll
    for (int r = 0; r < 4; ++r) {
        unsigned long long b = ~0ULL, s = ~0ULL;
#pragma unroll
        for (int t = 0; t < 16; ++t) {
            const int n = t * 16 + (lane & 15);
            float score = fmaf(-2.0f, acc[t][r], cs[t]);
            unsigned long long key =
                ((unsigned long long)fmap(score) << 32) | (unsigned)n;
            if (key < b) { s = b; b = key; }
            else if (key < s) { s = key; }
        }
#pragma unroll
        for (int d = 1; d < 16; d <<= 1) {
            unsigned long long ob = __shfl_xor(b, d);
            unsigned long long os = __shfl_xor(s, d);
            unsigned long long nb = ob < b ? ob : b;
            unsigned long long mx = ob < b ? b : ob;
            unsigned long long mn = os < s ? os : s;
            b = nb;
            s = mx < mn ? mx : mn;
        }
        if ((lane & 15) == 0) {
            const int row = (lane >> 4) * 4 + r;
            const size_t qg = (size_t)blockIdx.x * 64 + mt * 16 + row;
            out[qg] = (int)(unsigned)(b & 0xFFFFFFFFull);
            float f1 = unfmap((unsigned)(b >> 32));
            float f2 = unfmap((unsigned)(s >> 32));
            if (f2 - f1 < T_FLAG) {
                int idx = atomicAdd(cnt, 1);
                if (idx < WL_CAP) wl[idx] = (int)qg;
            }
        }
    }
}

// ---------------- Phase B: exact fp32 rescan, block-per-query ----------------
__global__ __launch_bounds__(256) void knn_refine(const float* __restrict__ x,
                                                  const float* __restrict__ cb,
                                                  const float* __restrict__ csq_g,
                                                  const int* __restrict__ wl,
                                                  const int* __restrict__ cnt,
                                                  int* __restrict__ out) {
    __shared__ unsigned long long sP[4];
    const int tid = threadIdx.x;           // == code index k
    const int lane = tid & 63;
    const int wave = tid >> 6;

    int n = *cnt;
    if (n > WL_CAP) n = WL_CAP;
    const float mycsq = csq_g[tid];
    const float4* cr = (const float4*)(cb + (size_t)tid * 128);

    for (int i = blockIdx.x; i < n; i += gridDim.x) {
        const int q = wl[i];
        const float4* qr = (const float4*)(x + (size_t)q * 128);
        float a0 = 0.f, a1 = 0.f, a2 = 0.f, a3 = 0.f;
#pragma unroll 8
        for (int c4 = 0; c4 < 32; ++c4) {
            float4 qv = qr[c4];            // broadcast (same addr all lanes)
            float4 cv = cr[c4];
            a0 = fmaf(qv.x, cv.x, a0);
            a1 = fmaf(qv.y, cv.y, a1);
            a2 = fmaf(qv.z, cv.z, a2);
            a3 = fmaf(qv.w, cv.w, a3);
        }
        float dot = (a0 + a1) + (a2 + a3);
        float score = fmaf(-2.0f, dot, mycsq);
        unsigned long long key =
            ((unsigned long long)fmap(score) << 32) | (unsigned)tid;
#pragma unroll
        for (int d = 1; d < 64; d <<= 1) {
            unsigned long long o = __shfl_xor(key, d);
            key = o < key ? o : key;
        }
        if (lane == 0) sP[wave] = key;
        __syncthreads();
        if (tid == 0) {
            unsigned long long b = sP[0];
            unsigned long long o;
            o = sP[1]; b = o < b ? o : b;
            o = sP[2]; b = o < b ? o : b;
            o = sP[3]; b = o < b ? o : b;
            out[q] = (int)(unsigned)(b & 0xFFFFFFFFull);
        }
        __syncthreads();
    }
}

extern "C" void kernel_launch(void* const* d_in, const int* in_sizes, int n_in,
                              void* d_out, int out_size, void* d_ws, size_t ws_size,
                              hipStream_t stream) {
    const float* x = (const float*)d_in[0];
    const float* cb = (const float*)d_in[1];
    int* out = (int*)d_out;

    char* ws = (char*)d_ws;
    int* cnt = (int*)(ws + CNT_OFF);
    float* csq = (float*)(ws + CSQ_OFF);
    __bf16* cbB = (__bf16*)(ws + CBB_OFF);
    int* wl = (int*)(ws + WL_OFF);

    const int M = in_sizes[0] / 128;     // 131072

    knn_prep<<<32, 256, 0, stream>>>(cb, cbB, csq, cnt);
    knn_mfma<<<M / 64, 256, 0, stream>>>(x, cbB, csq, out, cnt, wl);
    knn_refine<<<240, 256, 0, stream>>>(x, cb, csq, wl, cnt, out);
}

// Round 8
// 149.792 us; speedup vs baseline: 1.0472x; 1.0472x over previous
//
#include <hip/hip_runtime.h>
#include <hip/hip_bf16.h>

// 1-NN VQ via split-bf16 MFMA + exact fp32 refinement.
//   score[q][k] = csq[k] - 2*dot(q,c_k); out = argmin_k (lowest-k tie-break).
// Phase 0 (knn_prep): codebook -> bf16 hi/lo fragment-ready cbB (PART-MAJOR:
//   hi 64KB then lo 64KB) + csq; zeroes cnt.
// Phase A (knn_mfma): 128 q/block, 4 waves = 2 mgroups x 2 ngroups.
//   Wave = 4 mtiles x 8 ntiles (acc[4][8] floatx4 = 128 AGPR, B-reuse 4x).
//   B staged in LDS (64 KB/phase, ds_read_b128 conflict-free); A converted
//   from x in registers per (m,kb). dot ~= qh.ch + ql.ch + qh.cl (3-product,
//   err ~1.9e-3); top-2 merged across ngroups in LDS; gap < T=0.004 -> wl.
// Phase B (knn_refine): exact fp32 rescan, block-per-query.
// r8 vs r7: r7's launch_bounds(256,4) cut regs to 128/wave -> B-loads
//   serialized (MfmaUtil 12.8%). Root cause both r6/r7: 1 GB B-stream from
//   L2, latency-exposed. Fix: B in LDS + B-reuse 4 (traffic /4, latency =
//   LDS). kb loops unroll 1 (r4: spill); epilogue fully unrolled (r5: scratch).

typedef __bf16 bf16x8 __attribute__((ext_vector_type(8)));
typedef float  floatx4 __attribute__((ext_vector_type(4)));

#define MFMA16 __builtin_amdgcn_mfma_f32_16x16x32_bf16

#define CNT_OFF 0
#define CSQ_OFF 1024
#define CBB_OFF 4096
#define WL_OFF  (4096 + 131072)
#define WL_CAP  32768
#define T_FLAG  0.004f

__device__ __forceinline__ unsigned fmap(float f) {
    unsigned u = __float_as_uint(f);
    return (u & 0x80000000u) ? ~u : (u | 0x80000000u);
}
__device__ __forceinline__ float unfmap(unsigned u) {
    unsigned b = (u & 0x80000000u) ? (u ^ 0x80000000u) : ~u;
    return __uint_as_float(b);
}

// ---------------- Phase 0: codebook split, part-major fragment layout, csq ----------------
// cbB element index = part*32768 + ((t4*4 + kb)*64 + ln)*8 + j
//   part: 0=hi 1=lo; t4 = ntile 0..15; kb = k-chunk 0..3 (channels kb*32..);
//   lane ln: n = t4*16 + (ln&15), k = kb*32 + (ln>>4)*8 + j.
__global__ void knn_prep(const float* __restrict__ cb, __bf16* __restrict__ cbB,
                         float* __restrict__ csq, int* __restrict__ cnt) {
    const int tid = threadIdx.x;
    const int id = blockIdx.x * 256 + tid;       // 0..8191
    if (id == 0) *cnt = 0;
    const int part = id >> 12;
    const int rem = id & 4095;
    const int t4 = rem >> 8;
    const int kb = (rem >> 6) & 3;
    const int ln = id & 63;
    const int n = t4 * 16 + (ln & 15);
    const int k0 = kb * 32 + (ln >> 4) * 8;
    const float* src = cb + (size_t)n * 128 + k0;
    union { __bf16 h[8]; uint4 u; } p;
#pragma unroll
    for (int j = 0; j < 8; ++j) {
        float f = src[j];
        __bf16 hh = (__bf16)f;
        p.h[j] = (part == 0) ? hh : (__bf16)(f - (float)hh);
    }
    *(uint4*)(cbB + (size_t)id * 8) = p.u;

    if (blockIdx.x == 0) {
        const float4* row = (const float4*)(cb + (size_t)tid * 128);
        float a0 = 0.f, a1 = 0.f, a2 = 0.f, a3 = 0.f;
#pragma unroll 8
        for (int j = 0; j < 32; ++j) {
            float4 v = row[j];
            a0 = fmaf(v.x, v.x, a0);
            a1 = fmaf(v.y, v.y, a1);
            a2 = fmaf(v.z, v.z, a2);
            a3 = fmaf(v.w, v.w, a3);
        }
        csq[tid] = (a0 + a1) + (a2 + a3);
    }
}

// ---------------- Phase A: MFMA scores + top-2 + flag ----------------
__global__ __launch_bounds__(256, 2) void knn_mfma(const float* __restrict__ x,
                                                   const __bf16* __restrict__ cbB,
                                                   const float* __restrict__ csq_g,
                                                   int* __restrict__ out,
                                                   int* __restrict__ cnt,
                                                   int* __restrict__ wl) {
    __shared__ __bf16 sB[32768];                 // 64 KB: current B phase
    __shared__ float s_csq[256];                 // 1 KB
    __shared__ unsigned long long sWb[256];      // 2 KB: [ql][ng] best
    __shared__ unsigned long long sWs[256];      // 2 KB: [ql][ng] second

    const int tid = threadIdx.x;
    const int wave = tid >> 6;
    const int lane = tid & 63;
    const int mg = wave >> 1;                    // m-group 0..1
    const int ng = wave & 1;                     // n-group 0..1
    const int rl = lane & 15;                    // m/n col within tile
    const int cl = (lane >> 4) * 8;              // k offset within 32-chunk

    s_csq[tid] = csq_g[tid];

    // ---- stage B hi (64 KB) ----
    {
        const uint4* src = (const uint4*)cbB;    // part 0 at offset 0
        uint4* dst = (uint4*)sB;
#pragma unroll 4
        for (int i = 0; i < 16; ++i) dst[i * 256 + tid] = src[i * 256 + tid];
    }
    __syncthreads();

    floatx4 acc[4][8];
#pragma unroll
    for (int m = 0; m < 4; ++m)
#pragma unroll
        for (int t = 0; t < 8; ++t) acc[m][t] = (floatx4){0.f, 0.f, 0.f, 0.f};

    const float* xq = x + ((size_t)blockIdx.x * 128 + mg * 64) * 128;

    // ---- phase 1: kb 0..3 with B-hi: qh.ch + ql.ch ----
#pragma unroll 1
    for (int kb = 0; kb < 4; ++kb) {
        bf16x8 ah[4], al[4];
#pragma unroll
        for (int m = 0; m < 4; ++m) {
            const float* s = xq + (size_t)(m * 16 + rl) * 128 + kb * 32 + cl;
            float4 f0 = *(const float4*)(s);
            float4 f1 = *(const float4*)(s + 4);
            float f[8] = {f0.x, f0.y, f0.z, f0.w, f1.x, f1.y, f1.z, f1.w};
            union { __bf16 h[8]; bf16x8 v; } ph, pl;
#pragma unroll
            for (int j = 0; j < 8; ++j) {
                __bf16 hh = (__bf16)f[j];
                ph.h[j] = hh;
                pl.h[j] = (__bf16)(f[j] - (float)hh);
            }
            ah[m] = ph.v;
            al[m] = pl.v;
        }
#pragma unroll
        for (int t = 0; t < 8; ++t) {
            const int t4 = ng * 8 + t;
            bf16x8 b = *(const bf16x8*)(sB + (((t4 * 4 + kb) * 64 + lane) * 8));
            acc[0][t] = MFMA16(ah[0], b, acc[0][t], 0, 0, 0);
            acc[1][t] = MFMA16(ah[1], b, acc[1][t], 0, 0, 0);
            acc[2][t] = MFMA16(ah[2], b, acc[2][t], 0, 0, 0);
            acc[3][t] = MFMA16(ah[3], b, acc[3][t], 0, 0, 0);
            acc[0][t] = MFMA16(al[0], b, acc[0][t], 0, 0, 0);
            acc[1][t] = MFMA16(al[1], b, acc[1][t], 0, 0, 0);
            acc[2][t] = MFMA16(al[2], b, acc[2][t], 0, 0, 0);
            acc[3][t] = MFMA16(al[3], b, acc[3][t], 0, 0, 0);
        }
    }
    __syncthreads();   // phase-1 reads done before overwrite

    // ---- stage B lo (64 KB) ----
    {
        const uint4* src = (const uint4*)(cbB + 32768);   // part 1
        uint4* dst = (uint4*)sB;
#pragma unroll 4
        for (int i = 0; i < 16; ++i) dst[i * 256 + tid] = src[i * 256 + tid];
    }
    __syncthreads();

    // ---- phase 2: kb 0..3 with B-lo: qh.cl only ----
#pragma unroll 1
    for (int kb = 0; kb < 4; ++kb) {
        bf16x8 ah[4];
#pragma unroll
        for (int m = 0; m < 4; ++m) {
            const float* s = xq + (size_t)(m * 16 + rl) * 128 + kb * 32 + cl;
            float4 f0 = *(const float4*)(s);
            float4 f1 = *(const float4*)(s + 4);
            float f[8] = {f0.x, f0.y, f0.z, f0.w, f1.x, f1.y, f1.z, f1.w};
            union { __bf16 h[8]; bf16x8 v; } ph;
#pragma unroll
            for (int j = 0; j < 8; ++j) ph.h[j] = (__bf16)f[j];
            ah[m] = ph.v;
        }
#pragma unroll
        for (int t = 0; t < 8; ++t) {
            const int t4 = ng * 8 + t;
            bf16x8 b = *(const bf16x8*)(sB + (((t4 * 4 + kb) * 64 + lane) * 8));
            acc[0][t] = MFMA16(ah[0], b, acc[0][t], 0, 0, 0);
            acc[1][t] = MFMA16(ah[1], b, acc[1][t], 0, 0, 0);
            acc[2][t] = MFMA16(ah[2], b, acc[2][t], 0, 0, 0);
            acc[3][t] = MFMA16(ah[3], b, acc[3][t], 0, 0, 0);
        }
    }

    // ---- epilogue: per-wave top-2 over its 128 codes (FULLY unrolled) ----
    float cs[8];
#pragma unroll
    for (int t = 0; t < 8; ++t) cs[t] = s_csq[(ng * 8 + t) * 16 + rl];

#pragma unroll
    for (int m = 0; m < 4; ++m) {
#pragma unroll
        for (int r = 0; r < 4; ++r) {
            unsigned long long b = ~0ULL, s = ~0ULL;
#pragma unroll
            for (int t = 0; t < 8; ++t) {
                const int n = (ng * 8 + t) * 16 + rl;
                float score = fmaf(-2.0f, acc[m][t][r], cs[t]);
                unsigned long long key =
                    ((unsigned long long)fmap(score) << 32) | (unsigned)n;
                if (key < b) { s = b; b = key; }
                else if (key < s) { s = key; }
            }
#pragma unroll
            for (int d = 1; d < 16; d <<= 1) {
                unsigned long long ob = __shfl_xor(b, d);
                unsigned long long os = __shfl_xor(s, d);
                unsigned long long nb = ob < b ? ob : b;
                unsigned long long mx = ob < b ? b : ob;
                unsigned long long mn = os < s ? os : s;
                b = nb;
                s = mx < mn ? mx : mn;
            }
            if (rl == 0) {
                const int row = (lane >> 4);                     // 0..3
                const int ql = mg * 64 + m * 16 + row * 4 + r;   // 0..127
                sWb[ql * 2 + ng] = b;
                sWs[ql * 2 + ng] = s;
            }
        }
    }
    __syncthreads();

    // ---- merge the 2 n-groups, write out, flag near-ties ----
    if (tid < 128) {
        unsigned long long b0 = sWb[tid * 2 + 0], b1 = sWb[tid * 2 + 1];
        unsigned long long s0 = sWs[tid * 2 + 0], s1 = sWs[tid * 2 + 1];
        unsigned long long best = b0 < b1 ? b0 : b1;
        unsigned long long mx = b0 < b1 ? b1 : b0;
        unsigned long long mn = s0 < s1 ? s0 : s1;
        unsigned long long sec = mx < mn ? mx : mn;
        const size_t qg = (size_t)blockIdx.x * 128 + tid;
        out[qg] = (int)(unsigned)(best & 0xFFFFFFFFull);
        float f1 = unfmap((unsigned)(best >> 32));
        float f2 = unfmap((unsigned)(sec >> 32));
        if (f2 - f1 < T_FLAG) {
            int idx = atomicAdd(cnt, 1);
            if (idx < WL_CAP) wl[idx] = (int)qg;
        }
    }
}

// ---------------- Phase B: exact fp32 rescan, block-per-query ----------------
__global__ __launch_bounds__(256) void knn_refine(const float* __restrict__ x,
                                                  const float* __restrict__ cb,
                                                  const float* __restrict__ csq_g,
                                                  const int* __restrict__ wl,
                                                  const int* __restrict__ cnt,
                                                  int* __restrict__ out) {
    __shared__ unsigned long long sP[4];
    const int tid = threadIdx.x;           // == code index k
    const int lane = tid & 63;
    const int wave = tid >> 6;

    int n = *cnt;
    if (n > WL_CAP) n = WL_CAP;
    const float mycsq = csq_g[tid];
    const float4* cr = (const float4*)(cb + (size_t)tid * 128);

    for (int i = blockIdx.x; i < n; i += gridDim.x) {
        const int q = wl[i];
        const float4* qr = (const float4*)(x + (size_t)q * 128);
        float a0 = 0.f, a1 = 0.f, a2 = 0.f, a3 = 0.f;
#pragma unroll 8
        for (int c4 = 0; c4 < 32; ++c4) {
            float4 qv = qr[c4];            // broadcast (same addr all lanes)
            float4 cv = cr[c4];
            a0 = fmaf(qv.x, cv.x, a0);
            a1 = fmaf(qv.y, cv.y, a1);
            a2 = fmaf(qv.z, cv.z, a2);
            a3 = fmaf(qv.w, cv.w, a3);
        }
        float dot = (a0 + a1) + (a2 + a3);
        float score = fmaf(-2.0f, dot, mycsq);
        unsigned long long key =
            ((unsigned long long)fmap(score) << 32) | (unsigned)tid;
#pragma unroll
        for (int d = 1; d < 64; d <<= 1) {
            unsigned long long o = __shfl_xor(key, d);
            key = o < key ? o : key;
        }
        if (lane == 0) sP[wave] = key;
        __syncthreads();
        if (tid == 0) {
            unsigned long long b = sP[0];
            unsigned long long o;
            o = sP[1]; b = o < b ? o : b;
            o = sP[2]; b = o < b ? o : b;
            o = sP[3]; b = o < b ? o : b;
            out[q] = (int)(unsigned)(b & 0xFFFFFFFFull);
        }
        __syncthreads();
    }
}

extern "C" void kernel_launch(void* const* d_in, const int* in_sizes, int n_in,
                              void* d_out, int out_size, void* d_ws, size_t ws_size,
                              hipStream_t stream) {
    const float* x = (const float*)d_in[0];
    const float* cb = (const float*)d_in[1];
    int* out = (int*)d_out;

    char* ws = (char*)d_ws;
    int* cnt = (int*)(ws + CNT_OFF);
    float* csq = (float*)(ws + CSQ_OFF);
    __bf16* cbB = (__bf16*)(ws + CBB_OFF);
    int* wl = (int*)(ws + WL_OFF);

    const int M = in_sizes[0] / 128;     // 131072

    knn_prep<<<32, 256, 0, stream>>>(cb, cbB, csq, cnt);
    knn_mfma<<<M / 128, 256, 0, stream>>>(x, cbB, csq, out, cnt, wl);
    knn_refine<<<240, 256, 0, stream>>>(x, cb, csq, wl, cnt, out);
}

// Round 9
// 134.893 us; speedup vs baseline: 1.1629x; 1.1105x over previous
//
#include <hip/hip_runtime.h>
#include <hip/hip_bf16.h>

// 1-NN VQ via split-bf16 MFMA + exact fp32 refinement.
//   score[q][k] = csq[k] - 2*dot(q,c_k); out = argmin_k (lowest-k tie-break).
// Phase 0 (knn_prep): codebook -> bf16 hi/lo fragment-ready cbB (part-major) + csq.
// Phase A (knn_mfma): 128 q/block, 4 waves; wave = 2 m-tiles x ALL 16 n-tiles
//   (acc[2][16] = 128 AGPR). A (query) split-converted ONCE into registers
//   (ah/al[2][4] = 64 VGPR) in the prologue; K-loop body = ds_read_b128 + MFMA
//   only. B staged hi then lo in 64 KB LDS. dot ~= qh.ch + ql.ch + qh.cl
//   (3-product, score err ~1.9e-3); per-wave top-2 over all 256 codes (no
//   cross-wave merge); gap < T=0.004 -> worklist.
// Phase B (knn_refine): exact fp32 rescan, block-per-query.
// r9 vs r8: A-conv hoisted out of K-loop (r6/r7/r8 all ~15% MfmaUtil with
//   per-kb A work: global x loads + ~40 VALU conv per m per kb, done twice).
//   Wave owns all n -> epilogue merge + barrier removed. kb/t fully unrolled
//   (A const-indexed, r5 scratch lesson); unrolled body is LDS-only (r4's
//   spill was from unrolled GLOBAL loads). Budget: 64+~50 VGPR + 128 AGPR.

typedef __bf16 bf16x8 __attribute__((ext_vector_type(8)));
typedef float  floatx4 __attribute__((ext_vector_type(4)));

#define MFMA16 __builtin_amdgcn_mfma_f32_16x16x32_bf16

#define CNT_OFF 0
#define CSQ_OFF 1024
#define CBB_OFF 4096
#define WL_OFF  (4096 + 131072)
#define WL_CAP  32768
#define T_FLAG  0.004f

__device__ __forceinline__ unsigned fmap(float f) {
    unsigned u = __float_as_uint(f);
    return (u & 0x80000000u) ? ~u : (u | 0x80000000u);
}
__device__ __forceinline__ float unfmap(unsigned u) {
    unsigned b = (u & 0x80000000u) ? (u ^ 0x80000000u) : ~u;
    return __uint_as_float(b);
}

// ---------------- Phase 0: codebook split, part-major fragment layout, csq ----------------
// cbB element index = part*32768 + ((t4*4 + kb)*64 + ln)*8 + j
//   part: 0=hi 1=lo; t4 = ntile 0..15; kb = k-chunk 0..3;
//   lane ln: n = t4*16 + (ln&15), k = kb*32 + (ln>>4)*8 + j.
__global__ void knn_prep(const float* __restrict__ cb, __bf16* __restrict__ cbB,
                         float* __restrict__ csq, int* __restrict__ cnt) {
    const int tid = threadIdx.x;
    const int id = blockIdx.x * 256 + tid;       // 0..8191
    if (id == 0) *cnt = 0;
    const int part = id >> 12;
    const int rem = id & 4095;
    const int t4 = rem >> 8;
    const int kb = (rem >> 6) & 3;
    const int ln = id & 63;
    const int n = t4 * 16 + (ln & 15);
    const int k0 = kb * 32 + (ln >> 4) * 8;
    const float* src = cb + (size_t)n * 128 + k0;
    union { __bf16 h[8]; uint4 u; } p;
#pragma unroll
    for (int j = 0; j < 8; ++j) {
        float f = src[j];
        __bf16 hh = (__bf16)f;
        p.h[j] = (part == 0) ? hh : (__bf16)(f - (float)hh);
    }
    *(uint4*)(cbB + (size_t)id * 8) = p.u;

    if (blockIdx.x == 0) {
        const float4* row = (const float4*)(cb + (size_t)tid * 128);
        float a0 = 0.f, a1 = 0.f, a2 = 0.f, a3 = 0.f;
#pragma unroll 8
        for (int j = 0; j < 32; ++j) {
            float4 v = row[j];
            a0 = fmaf(v.x, v.x, a0);
            a1 = fmaf(v.y, v.y, a1);
            a2 = fmaf(v.z, v.z, a2);
            a3 = fmaf(v.w, v.w, a3);
        }
        csq[tid] = (a0 + a1) + (a2 + a3);
    }
}

// ---------------- Phase A: MFMA scores + top-2 + flag ----------------
__global__ __launch_bounds__(256, 2) void knn_mfma(const float* __restrict__ x,
                                                   const __bf16* __restrict__ cbB,
                                                   const float* __restrict__ csq_g,
                                                   int* __restrict__ out,
                                                   int* __restrict__ cnt,
                                                   int* __restrict__ wl) {
    __shared__ __bf16 sB[32768];                 // 64 KB: current B part
    __shared__ float s_csq[256];                 // 1 KB

    const int tid = threadIdx.x;
    const int wave = tid >> 6;
    const int lane = tid & 63;
    const int rl = lane & 15;                    // m/n col within tile
    const int kg = lane >> 4;                    // k-group 0..3

    s_csq[tid] = csq_g[tid];

    // ---- A: load + split-convert this wave's 2 m-tiles into registers ----
    const float* xq = x + ((size_t)blockIdx.x * 128 + wave * 32) * 128;
    bf16x8 ah[2][4], al[2][4];
#pragma unroll
    for (int m = 0; m < 2; ++m) {
#pragma unroll
        for (int kb = 0; kb < 4; ++kb) {
            const float* s = xq + (size_t)(m * 16 + rl) * 128 + kb * 32 + kg * 8;
            float4 f0 = *(const float4*)(s);
            float4 f1 = *(const float4*)(s + 4);
            float f[8] = {f0.x, f0.y, f0.z, f0.w, f1.x, f1.y, f1.z, f1.w};
            union { __bf16 h[8]; bf16x8 v; } ph, pl;
#pragma unroll
            for (int j = 0; j < 8; ++j) {
                __bf16 hh = (__bf16)f[j];
                ph.h[j] = hh;
                pl.h[j] = (__bf16)(f[j] - (float)hh);
            }
            ah[m][kb] = ph.v;
            al[m][kb] = pl.v;
        }
    }

    // ---- stage B hi (64 KB) ----
    {
        const uint4* src = (const uint4*)cbB;    // part 0
        uint4* dst = (uint4*)sB;
#pragma unroll 4
        for (int i = 0; i < 16; ++i) dst[i * 256 + tid] = src[i * 256 + tid];
    }
    __syncthreads();

    floatx4 acc[2][16];
#pragma unroll
    for (int m = 0; m < 2; ++m)
#pragma unroll
        for (int t = 0; t < 16; ++t) acc[m][t] = (floatx4){0.f, 0.f, 0.f, 0.f};

    // ---- hi phase: qh.ch + ql.ch ----
#pragma unroll
    for (int kb = 0; kb < 4; ++kb) {
#pragma unroll
        for (int t = 0; t < 16; ++t) {
            bf16x8 b = *(const bf16x8*)(sB + (((t * 4 + kb) * 64 + lane) * 8));
            acc[0][t] = MFMA16(ah[0][kb], b, acc[0][t], 0, 0, 0);
            acc[1][t] = MFMA16(ah[1][kb], b, acc[1][t], 0, 0, 0);
            acc[0][t] = MFMA16(al[0][kb], b, acc[0][t], 0, 0, 0);
            acc[1][t] = MFMA16(al[1][kb], b, acc[1][t], 0, 0, 0);
        }
    }
    __syncthreads();   // hi reads done before overwrite

    // ---- stage B lo (64 KB) ----
    {
        const uint4* src = (const uint4*)(cbB + 32768);   // part 1
        uint4* dst = (uint4*)sB;
#pragma unroll 4
        for (int i = 0; i < 16; ++i) dst[i * 256 + tid] = src[i * 256 + tid];
    }
    __syncthreads();

    // ---- lo phase: qh.cl only (ql.cl dropped) ----
#pragma unroll
    for (int kb = 0; kb < 4; ++kb) {
#pragma unroll
        for (int t = 0; t < 16; ++t) {
            bf16x8 b = *(const bf16x8*)(sB + (((t * 4 + kb) * 64 + lane) * 8));
            acc[0][t] = MFMA16(ah[0][kb], b, acc[0][t], 0, 0, 0);
            acc[1][t] = MFMA16(ah[1][kb], b, acc[1][t], 0, 0, 0);
        }
    }

    // ---- epilogue: per-wave top-2 over ALL 256 codes (FULLY unrolled) ----
    float cs[16];
#pragma unroll
    for (int t = 0; t < 16; ++t) cs[t] = s_csq[t * 16 + rl];

#pragma unroll
    for (int m = 0; m < 2; ++m) {
#pragma unroll
        for (int r = 0; r < 4; ++r) {
            unsigned long long b = ~0ULL, s = ~0ULL;
#pragma unroll
            for (int t = 0; t < 16; ++t) {
                const int n = t * 16 + rl;
                float score = fmaf(-2.0f, acc[m][t][r], cs[t]);
                unsigned long long key =
                    ((unsigned long long)fmap(score) << 32) | (unsigned)n;
                if (key < b) { s = b; b = key; }
                else if (key < s) { s = key; }
            }
#pragma unroll
            for (int d = 1; d < 16; d <<= 1) {
                unsigned long long ob = __shfl_xor(b, d);
                unsigned long long os = __shfl_xor(s, d);
                unsigned long long nb = ob < b ? ob : b;
                unsigned long long mx = ob < b ? b : ob;
                unsigned long long mn = os < s ? os : s;
                b = nb;
                s = mx < mn ? mx : mn;
            }
            if (rl == 0) {
                const size_t qg = (size_t)blockIdx.x * 128 + wave * 32
                                  + m * 16 + kg * 4 + r;
                out[qg] = (int)(unsigned)(b & 0xFFFFFFFFull);
                float f1 = unfmap((unsigned)(b >> 32));
                float f2 = unfmap((unsigned)(s >> 32));
                if (f2 - f1 < T_FLAG) {
                    int idx = atomicAdd(cnt, 1);
                    if (idx < WL_CAP) wl[idx] = (int)qg;
                }
            }
        }
    }
}

// ---------------- Phase B: exact fp32 rescan, block-per-query ----------------
__global__ __launch_bounds__(256) void knn_refine(const float* __restrict__ x,
                                                  const float* __restrict__ cb,
                                                  const float* __restrict__ csq_g,
                                                  const int* __restrict__ wl,
                                                  const int* __restrict__ cnt,
                                                  int* __restrict__ out) {
    __shared__ unsigned long long sP[4];
    const int tid = threadIdx.x;           // == code index k
    const int lane = tid & 63;
    const int wave = tid >> 6;

    int n = *cnt;
    if (n > WL_CAP) n = WL_CAP;
    const float mycsq = csq_g[tid];
    const float4* cr = (const float4*)(cb + (size_t)tid * 128);

    for (int i = blockIdx.x; i < n; i += gridDim.x) {
        const int q = wl[i];
        const float4* qr = (const float4*)(x + (size_t)q * 128);
        float a0 = 0.f, a1 = 0.f, a2 = 0.f, a3 = 0.f;
#pragma unroll 8
        for (int c4 = 0; c4 < 32; ++c4) {
            float4 qv = qr[c4];            // broadcast (same addr all lanes)
            float4 cv = cr[c4];
            a0 = fmaf(qv.x, cv.x, a0);
            a1 = fmaf(qv.y, cv.y, a1);
            a2 = fmaf(qv.z, cv.z, a2);
            a3 = fmaf(qv.w, cv.w, a3);
        }
        float dot = (a0 + a1) + (a2 + a3);
        float score = fmaf(-2.0f, dot, mycsq);
        unsigned long long key =
            ((unsigned long long)fmap(score) << 32) | (unsigned)tid;
#pragma unroll
        for (int d = 1; d < 64; d <<= 1) {
            unsigned long long o = __shfl_xor(key, d);
            key = o < key ? o : key;
        }
        if (lane == 0) sP[wave] = key;
        __syncthreads();
        if (tid == 0) {
            unsigned long long b = sP[0];
            unsigned long long o;
            o = sP[1]; b = o < b ? o : b;
            o = sP[2]; b = o < b ? o : b;
            o = sP[3]; b = o < b ? o : b;
            out[q] = (int)(unsigned)(b & 0xFFFFFFFFull);
        }
        __syncthreads();
    }
}

extern "C" void kernel_launch(void* const* d_in, const int* in_sizes, int n_in,
                              void* d_out, int out_size, void* d_ws, size_t ws_size,
                              hipStream_t stream) {
    const float* x = (const float*)d_in[0];
    const float* cb = (const float*)d_in[1];
    int* out = (int*)d_out;

    char* ws = (char*)d_ws;
    int* cnt = (int*)(ws + CNT_OFF);
    float* csq = (float*)(ws + CSQ_OFF);
    __bf16* cbB = (__bf16*)(ws + CBB_OFF);
    int* wl = (int*)(ws + WL_OFF);

    const int M = in_sizes[0] / 128;     // 131072

    knn_prep<<<32, 256, 0, stream>>>(cb, cbB, csq, cnt);
    knn_mfma<<<M / 128, 256, 0, stream>>>(x, cbB, csq, out, cnt, wl);
    knn_refine<<<240, 256, 0, stream>>>(x, cb, csq, wl, cnt, out);
}